// Round 2
// baseline (360.844 us; speedup 1.0000x reference)
//
#include <hip/hip_runtime.h>
#include <hip/hip_bf16.h>
#include <math.h>

#define BB 2
#define SS 2048
#define EE 2048
#define NQ 16
#define NKV 4
#define HD 128
#define WINDOW 512

typedef __hip_bfloat16 bf16;
typedef short short8 __attribute__((ext_vector_type(8)));   // 8 bf16 (4 VGPRs)
typedef float f32x4 __attribute__((ext_vector_type(4)));

__device__ __forceinline__ float toF(bf16 v) { return __bfloat162float(v); }
__device__ __forceinline__ bf16 toB(float v) { return __float2bfloat16(v); }

// async global->LDS, 16B per lane. LDS dest = wave-uniform base + lane*16.
__device__ __forceinline__ void gld_lds16(const void* g, void* l) {
    __builtin_amdgcn_global_load_lds(
        (const __attribute__((address_space(1))) void*)g,
        (__attribute__((address_space(3))) void*)l, 16, 0, 0);
}

// ---------------------------------------------------------------------------
// fp32 -> bf16 elementwise (n % 4 == 0)
// ---------------------------------------------------------------------------
__global__ __launch_bounds__(256) void convert_bf16(const float* __restrict__ in,
                                                    bf16* __restrict__ out, int n) {
    int i = (blockIdx.x * 256 + threadIdx.x) * 4;
    if (i >= n) return;
    const float4 v = *(const float4*)(in + i);
    bf16 o[4] = {toB(v.x), toB(v.y), toB(v.z), toB(v.w)};
    *(uint2*)(out + i) = *(const uint2*)o;
}

// ---------------------------------------------------------------------------
// fp32 [K][N] -> bf16 [N][K] transpose. Generic (Wo).
// ---------------------------------------------------------------------------
__global__ __launch_bounds__(256) void convert_transpose(const float* __restrict__ in,
                                                         bf16* __restrict__ out,
                                                         int K, int N) {
    __shared__ float tile[32][33];
    const int t = threadIdx.x;
    const int tx = t & 31, ty = t >> 5;   // 32 x 8
    const int n0 = blockIdx.x * 32, k0 = blockIdx.y * 32;
#pragma unroll
    for (int r = 0; r < 4; r++)
        tile[ty + r * 8][tx] = in[(size_t)(k0 + ty + r * 8) * N + n0 + tx];
    __syncthreads();
#pragma unroll
    for (int r = 0; r < 4; r++)
        out[(size_t)(n0 + ty + r * 8) * K + k0 + tx] = toB(tile[tx][ty + r * 8]);
}

// ---------------------------------------------------------------------------
// Fused Wq/Wk/Wv transpose into packed [3072][2048] bf16.
// ---------------------------------------------------------------------------
__global__ __launch_bounds__(256) void convert_transpose_qkv(
    const float* __restrict__ Wq, const float* __restrict__ Wk,
    const float* __restrict__ Wv, bf16* __restrict__ out) {
    __shared__ float tile[32][33];
    const int t = threadIdx.x;
    const int tx = t & 31, ty = t >> 5;
    const int n0 = blockIdx.x * 32, k0 = blockIdx.y * 32;
    const float* src; int N, nl0;
    if (n0 < 2048)      { src = Wq; N = 2048; nl0 = n0; }
    else if (n0 < 2560) { src = Wk; N = 512;  nl0 = n0 - 2048; }
    else                { src = Wv; N = 512;  nl0 = n0 - 2560; }
#pragma unroll
    for (int r = 0; r < 4; r++)
        tile[ty + r * 8][tx] = src[(size_t)(k0 + ty + r * 8) * N + nl0 + tx];
    __syncthreads();
#pragma unroll
    for (int r = 0; r < 4; r++)
        out[(size_t)(n0 + ty + r * 8) * 2048 + k0 + tx] = toB(tile[tx][ty + r * 8]);
}

// ---------------------------------------------------------------------------
// 256x256 8-phase MFMA GEMM (T2+T3+T4+T5 template, plain HIP).
// BK=64, 512 threads = 8 waves (2M x 4N), per-wave output 128x64.
// LDS 128 KiB: A,B each 2 buf x 2 half x [128][64] bf16.
// Per K-tile: 4 phases of 16 MFMA (i-quadrants). Raw s_barrier between
// phases (NO waitcnt drain); stages for tile t+1 front-loaded into phases
// 0-1 of tile t so the single vmcnt(0) at the tile boundary is issued
// ~2-3 phases (>800 cyc) early. XOR swizzle: 16B slot s of row r holds
// k-group s^(r&7) -> ds_read_b128 frag reads hit 8 lanes/bank-quad.
// MODE 0: fp32 out + bias. MODE 1: packed QKV split, RoPE fused for Q/K,
// V stored transposed [b][hkv][d][s].
// ---------------------------------------------------------------------------
template <int MODE>
__global__ __launch_bounds__(512, 2) void mfma_gemm256(
    const bf16* __restrict__ A, const bf16* __restrict__ BT,
    const float* __restrict__ b0, const float* __restrict__ b1,
    const float* __restrict__ b2,
    float* __restrict__ Yf,
    bf16* __restrict__ Yq, bf16* __restrict__ Yk, bf16* __restrict__ Yv,
    int M, int N, int K) {
    __shared__ __align__(16) bf16 As[2][2][128 * 64];   // 64 KiB
    __shared__ __align__(16) bf16 Bs[2][2][128 * 64];   // 64 KiB

    const int t = threadIdx.x;
    const int lane = t & 63;
    const int w = t >> 6;          // 0..7
    const int wm = w >> 2;         // 0..1  -> A half
    const int wn = w & 3;          // 0..3  -> B half = wn>>1
    const int m0 = blockIdx.y * 256, n0 = blockIdx.x * 256;
    const int lr = lane & 15;
    const int lq = lane >> 4;

    const int srow8 = lane >> 3;   // row within 8-row staging chunk
    const int sslot = lane & 7;    // 16B slot within 128B row
    const int NT = K >> 6;

    // stage half h (128 rows x 64 cols) of a K-tile into buffer bi.
    auto stA = [&](int bi, int h, int kt) {
#pragma unroll
        for (int l = 0; l < 2; l++) {
            const int c = w * 2 + l;
            const int r = c * 8 + srow8;
            const int g = sslot ^ (r & 7);
            gld_lds16(A + (size_t)(m0 + h * 128 + r) * K + kt * 64 + g * 8,
                      &As[bi][h][c * 512]);
        }
    };
    auto stB = [&](int bi, int h, int kt) {
#pragma unroll
        for (int l = 0; l < 2; l++) {
            const int c = w * 2 + l;
            const int r = c * 8 + srow8;
            const int g = sslot ^ (r & 7);
            gld_lds16(BT + (size_t)(n0 + h * 128 + r) * K + kt * 64 + g * 8,
                      &Bs[bi][h][c * 512]);
        }
    };

    f32x4 acc[8][4];
#pragma unroll
    for (int i = 0; i < 8; i++)
#pragma unroll
        for (int j = 0; j < 4; j++) acc[i][j] = (f32x4)0.f;

    // prologue: stage tile 0 into buf 0
    stA(0, 0, 0); stA(0, 1, 0); stB(0, 0, 0); stB(0, 1, 0);
    asm volatile("s_waitcnt vmcnt(0)" ::: "memory");
    __builtin_amdgcn_s_barrier();

    const int brh0 = (wn & 1) * 64;   // B row base within half
    const int bh = wn >> 1;

    for (int kt = 0; kt < NT; kt++) {
        const int bi = kt & 1;
        const bool pf = (kt + 1 < NT);
        const bf16* Aw = &As[bi][wm][0];
        const bf16* Bw = &Bs[bi][bh][0];
        short8 bfr[4][2];
#pragma unroll
        for (int p = 0; p < 4; p++) {
            // front-loaded stage of next tile (other buffer)
            if (p == 0 && pf) { stA(bi ^ 1, 0, kt + 1); stA(bi ^ 1, 1, kt + 1); }
            if (p == 1 && pf) { stB(bi ^ 1, 0, kt + 1); stB(bi ^ 1, 1, kt + 1); }
            // ds reads for this phase's MFMAs
            if (p == 0) {
#pragma unroll
                for (int j = 0; j < 4; j++)
#pragma unroll
                    for (int kk = 0; kk < 2; kk++) {
                        const int rh = brh0 + j * 16 + lr;
                        const int slot = ((kk << 2) + lq) ^ (lr & 7);
                        bfr[j][kk] = *(const short8*)(Bw + rh * 64 + slot * 8);
                    }
            }
            short8 afr[2][2];
#pragma unroll
            for (int i2 = 0; i2 < 2; i2++)
#pragma unroll
                for (int kk = 0; kk < 2; kk++) {
                    const int rh = (p * 2 + i2) * 16 + lr;
                    const int slot = ((kk << 2) + lq) ^ (lr & 7);
                    afr[i2][kk] = *(const short8*)(Aw + rh * 64 + slot * 8);
                }
            __builtin_amdgcn_s_barrier();
            __builtin_amdgcn_s_setprio(1);
#pragma unroll
            for (int i2 = 0; i2 < 2; i2++)
#pragma unroll
                for (int j = 0; j < 4; j++)
#pragma unroll
                    for (int kk = 0; kk < 2; kk++)
                        acc[p * 2 + i2][j] = __builtin_amdgcn_mfma_f32_16x16x32_bf16(
                            afr[i2][kk], bfr[j][kk], acc[p * 2 + i2][j], 0, 0, 0);
            __builtin_amdgcn_s_setprio(0);
            if (p < 3) {
                __builtin_amdgcn_s_barrier();
            } else {
                // K-tile boundary: loads for tile kt+1 were issued >=2 phases
                // ago; drain then release the other buffer for reads.
                asm volatile("s_waitcnt vmcnt(0)" ::: "memory");
                __builtin_amdgcn_s_barrier();
            }
        }
    }

    if (MODE == 0) {
#pragma unroll
        for (int j = 0; j < 4; j++) {
            const int col = n0 + wn * 64 + j * 16 + lr;
            const float bj = b0[col];
#pragma unroll
            for (int i = 0; i < 8; i++) {
                const int row = m0 + wm * 128 + i * 16 + lq * 4;
#pragma unroll
                for (int r = 0; r < 4; r++)
                    Yf[(size_t)(row + r) * N + col] = acc[i][j][r] + bj;
            }
        }
    } else if (n0 < 2560) {
        // Q or K with fused RoPE
        bf16* outp; const float* bias; int ldc, c0;
        if (n0 < 2048) { outp = Yq; bias = b0; ldc = 2048; c0 = n0; }
        else           { outp = Yk; bias = b1; ldc = 512;  c0 = n0 - 2048; }
#pragma unroll
        for (int j = 0; j < 4; j++) {
            const int col = c0 + wn * 64 + j * 16 + lr;
            const float bj = bias[col];
            const int d2 = (col & 127) >> 1;
            const bool odd = col & 1;
            const float freq = __expf(-0.14384103622589045f * (float)d2); // ln(1e4)*2/128
#pragma unroll
            for (int i = 0; i < 8; i++) {
                const int row = m0 + wm * 128 + i * 16 + lq * 4;
#pragma unroll
                for (int r = 0; r < 4; r++) {
                    const float v = acc[i][j][r] + bj;
                    const float p = __shfl_xor(v, 1, 64);
                    const float ang = (float)((row + r) & (SS - 1)) * freq;
                    float sn, cs;
                    __sincosf(ang, &sn, &cs);
                    const float o = odd ? (p * sn + v * cs) : (v * cs - p * sn);
                    outp[(size_t)(row + r) * ldc + col] = toB(o);
                }
            }
        }
    } else {
        // V: store transposed [b][hkv][d][s]; 4 acc rows = 4 consecutive s.
        const int c0 = n0 - 2560;
#pragma unroll
        for (int j = 0; j < 4; j++) {
            const int col = c0 + wn * 64 + j * 16 + lr;   // 0..511
            const float bj = b2[col];
            const int hkv = col >> 7, d = col & 127;
#pragma unroll
            for (int i = 0; i < 8; i++) {
                const int row = m0 + wm * 128 + i * 16 + lq * 4;
                const int bb = row >> 11, sr = row & (SS - 1);
                union { bf16 b[4]; uint2 u; } o4;
#pragma unroll
                for (int r = 0; r < 4; r++) o4.b[r] = toB(acc[i][j][r] + bj);
                *(uint2*)(Yv + (((size_t)bb * NKV + hkv) * HD + d) * SS + sr) = o4.u;
            }
        }
    }
}

// ---------------------------------------------------------------------------
// MFMA flash attention, windowed causal, GQA (unchanged from round 1).
// ---------------------------------------------------------------------------
__global__ __launch_bounds__(256) void attn_mfma(const bf16* __restrict__ Q,
                                                 const bf16* __restrict__ K,
                                                 const bf16* __restrict__ VT,
                                                 bf16* __restrict__ Oout) {
    __shared__ bf16 Ks[64 * 128];      // [key][d], slot-swizzled
    __shared__ bf16 Vs[128 * 64];      // [d][key] (V^T), slot-swizzled
    __shared__ bf16 Ps[4 * 16 * 72];   // per-wave P tile, pad 72

    const int t = threadIdx.x;
    const int lane = t & 63;
    const int w = t >> 6;
    const int q0 = blockIdx.x * 64;
    const int h = blockIdx.y;
    const int b = blockIdx.z;
    const int hkv = h >> 2;
    const int lr = lane & 15;
    const int lq = lane >> 4;
    const float scale = 0.08838834764831845f;  // 1/sqrt(128)

    short8 aq[4];
    {
        const int q = q0 + w * 16 + lr;
        const bf16* qp = Q + (((size_t)b * SS + q) * NQ + h) * HD + lq * 8;
#pragma unroll
        for (int ks = 0; ks < 4; ks++) aq[ks] = *(const short8*)(qp + ks * 32);
    }

    const int krow = w * 16 + (lane >> 4);
    const int vrow = w * 32 + (lane >> 3);
    const bf16* Kbase = K + ((size_t)b * SS * NKV + hkv) * HD;
    const bf16* Vbase = VT + (((size_t)b * NKV + hkv) * HD) * SS;

    f32x4 Oa[8];
#pragma unroll
    for (int nb = 0; nb < 8; nb++) Oa[nb] = (f32x4)0.f;
    float mprev[4] = {-3.0e38f, -3.0e38f, -3.0e38f, -3.0e38f};
    float lsum[4] = {0.f, 0.f, 0.f, 0.f};

    bf16* Pw = Ps + w * 16 * 72;
    const int jstart = (q0 >= WINDOW) ? (q0 - WINDOW) : 0;

    for (int c0 = jstart; c0 <= q0; c0 += 64) {
        __syncthreads();
#pragma unroll
        for (int s = 0; s < 4; s++) {
            const int r_ = krow + s * 4;
            const int g_ = (lane & 15) ^ (r_ & 7);
            gld_lds16(Kbase + (size_t)(c0 + r_) * (NKV * HD) + g_ * 8,
                      Ks + (w * 16 + s * 4) * 128);
        }
#pragma unroll
        for (int s = 0; s < 4; s++) {
            const int d_ = vrow + s * 8;
            const int g_ = (lane & 7) ^ (d_ & 7);
            gld_lds16(Vbase + (size_t)d_ * SS + c0 + g_ * 8,
                      Vs + (w * 32 + s * 8) * 64);
        }
        __syncthreads();

        f32x4 sa[4];
#pragma unroll
        for (int nb = 0; nb < 4; nb++) sa[nb] = (f32x4)0.f;
#pragma unroll
        for (int ks = 0; ks < 4; ks++) {
#pragma unroll
            for (int nb = 0; nb < 4; nb++) {
                const int slot = (ks * 4 + lq) ^ (lr & 7);
                short8 bk = *(const short8*)(Ks + (nb * 16 + lr) * 128 + slot * 8);
                sa[nb] = __builtin_amdgcn_mfma_f32_16x16x32_bf16(aq[ks], bk, sa[nb], 0, 0, 0);
            }
        }

        const int rowb = q0 + w * 16 + lq * 4;
        const bool noMask = (c0 + 63 <= q0 + w * 16) &&
                            (q0 + w * 16 + 15 - c0 <= WINDOW);
        float pr[4][4], alpha[4];
#pragma unroll
        for (int r = 0; r < 4; r++) {
            const int row = rowb + r;
            float sv[4];
            float mx = -3.0e38f;
            if (noMask) {
#pragma unroll
                for (int nb = 0; nb < 4; nb++) {
                    const float s = sa[nb][r] * scale;
                    sv[nb] = s;
                    mx = fmaxf(mx, s);
                }
            } else {
#pragma unroll
                for (int nb = 0; nb < 4; nb++) {
                    const int col = c0 + nb * 16 + lr;
                    const bool valid = (col <= row) && (row - col <= WINDOW);
                    const float s = valid ? sa[nb][r] * scale : -3.0e38f;
                    sv[nb] = s;
                    mx = fmaxf(mx, s);
                }
            }
#pragma unroll
            for (int off = 1; off < 16; off <<= 1) mx = fmaxf(mx, __shfl_xor(mx, off, 64));
            const float mn = fmaxf(fmaxf(mprev[r], mx), -1.0e30f);
            alpha[r] = __expf(mprev[r] - mn);
            mprev[r] = mn;
            float rs = 0.f;
#pragma unroll
            for (int nb = 0; nb < 4; nb++) {
                const float p = __expf(sv[nb] - mn);
                pr[r][nb] = p;
                rs += p;
            }
#pragma unroll
            for (int off = 1; off < 16; off <<= 1) rs += __shfl_xor(rs, off, 64);
            lsum[r] = lsum[r] * alpha[r] + rs;
        }

#pragma unroll
        for (int r = 0; r < 4; r++)
#pragma unroll
            for (int nb = 0; nb < 4; nb++)
                Pw[(lq * 4 + r) * 72 + nb * 16 + lr] = toB(pr[r][nb]);

#pragma unroll
        for (int nb = 0; nb < 8; nb++)
#pragma unroll
            for (int r = 0; r < 4; r++) Oa[nb][r] *= alpha[r];
#pragma unroll
        for (int ks = 0; ks < 2; ks++) {
            short8 pa = *(const short8*)(Pw + lr * 72 + ks * 32 + lq * 8);
#pragma unroll
            for (int nb = 0; nb < 8; nb++) {
                const int slot = (ks * 4 + lq) ^ (lr & 7);
                short8 bv = *(const short8*)(Vs + (nb * 16 + lr) * 64 + slot * 8);
                Oa[nb] = __builtin_amdgcn_mfma_f32_16x16x32_bf16(pa, bv, Oa[nb], 0, 0, 0);
            }
        }
    }

    float linv[4];
#pragma unroll
    for (int r = 0; r < 4; r++) linv[r] = 1.f / lsum[r];
    const int rowb = q0 + w * 16 + lq * 4;
#pragma unroll
    for (int nb = 0; nb < 8; nb++)
#pragma unroll
        for (int r = 0; r < 4; r++)
            Oout[(((size_t)b * SS + rowb + r) * NQ + h) * HD + nb * 16 + lr] =
                toB(Oa[nb][r] * linv[r]);
}

// ---------------------------------------------------------------------------
extern "C" void kernel_launch(void* const* d_in, const int* in_sizes, int n_in,
                              void* d_out, int out_size, void* d_ws, size_t ws_size,
                              hipStream_t stream) {
    const float* x  = (const float*)d_in[0];
    const float* Wq = (const float*)d_in[1];
    const float* bq = (const float*)d_in[2];
    const float* Wk = (const float*)d_in[3];
    const float* bk = (const float*)d_in[4];
    const float* Wv = (const float*)d_in[5];
    const float* bv = (const float*)d_in[6];
    const float* Wo = (const float*)d_in[7];
    const float* bo = (const float*)d_in[8];
    float* out = (float*)d_out;

    const int M   = BB * SS;       // 4096
    const int DQ  = NQ * HD;       // 2048
    const int DKV = NKV * HD;      // 512
    const int NPK = DQ + 2 * DKV;  // 3072

    bf16* xb     = (bf16*)d_ws;                       // 4096*2048
    bf16* WqkvT  = xb + (size_t)M * EE;               // 3072*2048
    bf16* WoT    = WqkvT + (size_t)NPK * EE;          // 2048*2048
    bf16* Qb     = WoT + (size_t)EE * DQ;             // 4096*2048 (attn out in-place)
    bf16* Kb     = Qb + (size_t)M * DQ;               // 4096*512
    bf16* Vb     = Kb + (size_t)M * DKV;              // 4096*512  (V^T layout)

    convert_bf16<<<(M * EE / 4 + 255) / 256, 256, 0, stream>>>(x, xb, M * EE);
    convert_transpose_qkv<<<dim3(NPK / 32, EE / 32), 256, 0, stream>>>(Wq, Wk, Wv, WqkvT);
    convert_transpose<<<dim3(DQ / 32, DQ / 32), 256, 0, stream>>>(Wo, WoT, DQ, EE);

    // fused QKV projection + bias + RoPE (256^2 8-phase MFMA); V transposed
    mfma_gemm256<1><<<dim3(NPK / 256, M / 256), 512, 0, stream>>>(
        xb, WqkvT, bq, bk, bv, nullptr, Qb, Kb, Vb, M, NPK, EE);

    attn_mfma<<<dim3(SS / 64, NQ, BB), 256, 0, stream>>>(Qb, Kb, Vb, Qb);

    mfma_gemm256<0><<<dim3(EE / 256, M / 256), 512, 0, stream>>>(
        Qb, WoT, bo, nullptr, nullptr, out, nullptr, nullptr, nullptr, M, EE, DQ);
}

// Round 3
// 327.514 us; speedup vs baseline: 1.1018x; 1.1018x over previous
//
#include <hip/hip_runtime.h>
#include <hip/hip_bf16.h>
#include <math.h>

#define BB 2
#define SS 2048
#define EE 2048
#define NQ 16
#define NKV 4
#define HD 128
#define WINDOW 512

typedef __hip_bfloat16 bf16;
typedef short short8 __attribute__((ext_vector_type(8)));   // 8 bf16 (4 VGPRs)
typedef float f32x4 __attribute__((ext_vector_type(4)));

__device__ __forceinline__ float toF(bf16 v) { return __bfloat162float(v); }
__device__ __forceinline__ bf16 toB(float v) { return __float2bfloat16(v); }

// async global->LDS, 16B per lane. LDS dest = wave-uniform base + lane*16.
__device__ __forceinline__ void gld_lds16(const void* g, void* l) {
    __builtin_amdgcn_global_load_lds(
        (const __attribute__((address_space(1))) void*)g,
        (__attribute__((address_space(3))) void*)l, 16, 0, 0);
}

template <int V> __device__ __forceinline__ void waitvm() {
    if constexpr (V == 8)      asm volatile("s_waitcnt vmcnt(8)" ::: "memory");
    else if constexpr (V == 6) asm volatile("s_waitcnt vmcnt(6)" ::: "memory");
    else if constexpr (V == 4) asm volatile("s_waitcnt vmcnt(4)" ::: "memory");
    else if constexpr (V == 3) asm volatile("s_waitcnt vmcnt(3)" ::: "memory");
    else                       asm volatile("s_waitcnt vmcnt(0)" ::: "memory");
}

// ---------------------------------------------------------------------------
// fp32 -> bf16 elementwise (n % 4 == 0)
// ---------------------------------------------------------------------------
__global__ __launch_bounds__(256) void convert_bf16(const float* __restrict__ in,
                                                    bf16* __restrict__ out, int n) {
    int i = (blockIdx.x * 256 + threadIdx.x) * 4;
    if (i >= n) return;
    const float4 v = *(const float4*)(in + i);
    bf16 o[4] = {toB(v.x), toB(v.y), toB(v.z), toB(v.w)};
    *(uint2*)(out + i) = *(const uint2*)o;
}

// ---------------------------------------------------------------------------
// fp32 [K][N] -> bf16 [N][K] transpose. Generic (Wo).
// ---------------------------------------------------------------------------
__global__ __launch_bounds__(256) void convert_transpose(const float* __restrict__ in,
                                                         bf16* __restrict__ out,
                                                         int K, int N) {
    __shared__ float tile[32][33];
    const int t = threadIdx.x;
    const int tx = t & 31, ty = t >> 5;   // 32 x 8
    const int n0 = blockIdx.x * 32, k0 = blockIdx.y * 32;
#pragma unroll
    for (int r = 0; r < 4; r++)
        tile[ty + r * 8][tx] = in[(size_t)(k0 + ty + r * 8) * N + n0 + tx];
    __syncthreads();
#pragma unroll
    for (int r = 0; r < 4; r++)
        out[(size_t)(n0 + ty + r * 8) * K + k0 + tx] = toB(tile[tx][ty + r * 8]);
}

// ---------------------------------------------------------------------------
// Fused Wq/Wk/Wv transpose into packed [3072][2048] bf16.
// ---------------------------------------------------------------------------
__global__ __launch_bounds__(256) void convert_transpose_qkv(
    const float* __restrict__ Wq, const float* __restrict__ Wk,
    const float* __restrict__ Wv, bf16* __restrict__ out) {
    __shared__ float tile[32][33];
    const int t = threadIdx.x;
    const int tx = t & 31, ty = t >> 5;
    const int n0 = blockIdx.x * 32, k0 = blockIdx.y * 32;
    const float* src; int N, nl0;
    if (n0 < 2048)      { src = Wq; N = 2048; nl0 = n0; }
    else if (n0 < 2560) { src = Wk; N = 512;  nl0 = n0 - 2048; }
    else                { src = Wv; N = 512;  nl0 = n0 - 2560; }
#pragma unroll
    for (int r = 0; r < 4; r++)
        tile[ty + r * 8][tx] = src[(size_t)(k0 + ty + r * 8) * N + nl0 + tx];
    __syncthreads();
#pragma unroll
    for (int r = 0; r < 4; r++)
        out[(size_t)(n0 + ty + r * 8) * 2048 + k0 + tx] = toB(tile[tx][ty + r * 8]);
}

// ---------------------------------------------------------------------------
// MFMA GEMM v3: k-slice pipelined, counted vmcnt (never 0 mid-loop).
// BMxBN tile, BK=64 staged as TWO independent 32-k slices; LDS layout
// [buf][slice][rows][32] so each slice is one contiguous global_load_lds
// unit and slices are consumed in staged order.
// Per K-tile: 2 phases. Phase kk: {issue stage slice kk of tile t+1 ->
// buf^1; vmcnt(2*PL) = wait for slice kk of tile t (issued 2 phases ago);
// barrier; ds-read frags; MFMA cluster}. Tile-end barrier = WAR guard.
// 512 threads = 8 waves (WARPS_M x WARPS_N). MODE 0: fp32 out + bias.
// MODE 1: packed QKV split, RoPE fused Q/K, V stored transposed.
// ---------------------------------------------------------------------------
template <int MODE, int BM, int BN, int WARPS_M>
__global__ __launch_bounds__(512, 2) void mfma_gemm_v3(
    const bf16* __restrict__ A, const bf16* __restrict__ BT,
    const float* __restrict__ b0, const float* __restrict__ b1,
    const float* __restrict__ b2,
    float* __restrict__ Yf,
    bf16* __restrict__ Yq, bf16* __restrict__ Yk, bf16* __restrict__ Yv,
    int M, int N, int K) {
    constexpr int WARPS_N = 8 / WARPS_M;
    constexpr int NI = BM / WARPS_M / 16;   // A frags per wave per phase
    constexpr int NJ = BN / WARPS_N / 16;   // B frags per wave per phase
    constexpr int LA = BM / 128;            // gld_lds per A slice per thread
    constexpr int LB = BN / 128;
    constexpr int PL = LA + LB;             // loads per slice-stage

    __shared__ __align__(16) bf16 As[2][2][BM * 32];
    __shared__ __align__(16) bf16 Bs[2][2][BN * 32];

    const int t = threadIdx.x;
    const int lane = t & 63;
    const int w = t >> 6;                   // 0..7
    const int wm = w / WARPS_N;
    const int wn = w % WARPS_N;
    const int m0 = blockIdx.y * BM, n0 = blockIdx.x * BN;
    const int lr = lane & 15;
    const int lq = lane >> 4;
    const int NT = K >> 6;

    // stage slice kk of tile kt into buffer bi (contiguous, linear dest)
    auto stA = [&](int bi, int kk, int kt) {
#pragma unroll
        for (int l = 0; l < LA; l++) {
            const int c = w * LA + l;       // 16-row chunk
            gld_lds16(A + (size_t)(m0 + c * 16 + (lane >> 2)) * K +
                          kt * 64 + kk * 32 + (lane & 3) * 8,
                      &As[bi][kk][c * 512]);
        }
    };
    auto stB = [&](int bi, int kk, int kt) {
#pragma unroll
        for (int l = 0; l < LB; l++) {
            const int c = w * LB + l;
            gld_lds16(BT + (size_t)(n0 + c * 16 + (lane >> 2)) * K +
                           kt * 64 + kk * 32 + (lane & 3) * 8,
                      &Bs[bi][kk][c * 512]);
        }
    };

    f32x4 acc[NI][NJ];
#pragma unroll
    for (int i = 0; i < NI; i++)
#pragma unroll
        for (int j = 0; j < NJ; j++) acc[i][j] = (f32x4)0.f;

    auto phase = [&](int bi, int kk) {
        const bf16* Aslc = &As[bi][kk][0];
        const bf16* Bslc = &Bs[bi][kk][0];
        short8 af[NI], bfv[NJ];
#pragma unroll
        for (int i = 0; i < NI; i++)
            af[i] = *(const short8*)(Aslc + (wm * (NI * 16) + i * 16 + lr) * 32 + lq * 8);
#pragma unroll
        for (int j = 0; j < NJ; j++)
            bfv[j] = *(const short8*)(Bslc + (wn * (NJ * 16) + j * 16 + lr) * 32 + lq * 8);
        __builtin_amdgcn_s_setprio(1);
#pragma unroll
        for (int i = 0; i < NI; i++)
#pragma unroll
            for (int j = 0; j < NJ; j++)
                acc[i][j] = __builtin_amdgcn_mfma_f32_16x16x32_bf16(af[i], bfv[j],
                                                                    acc[i][j], 0, 0, 0);
        __builtin_amdgcn_s_setprio(0);
    };

    // prologue: both slices of tile 0 -> buf 0
    stA(0, 0, 0); stB(0, 0, 0);
    stA(0, 1, 0); stB(0, 1, 0);

    for (int kt = 0; kt < NT; kt++) {
        const int bi = kt & 1;
        const bool pf = (kt + 1 < NT);
        // ---- phase kk=0
        if (pf) { stA(bi ^ 1, 0, kt + 1); stB(bi ^ 1, 0, kt + 1); waitvm<2 * PL>(); }
        else    { waitvm<PL>(); }
        __builtin_amdgcn_s_barrier();
        __builtin_amdgcn_sched_barrier(0);
        phase(bi, 0);
        // ---- phase kk=1
        if (pf) { stA(bi ^ 1, 1, kt + 1); stB(bi ^ 1, 1, kt + 1); waitvm<2 * PL>(); }
        else    { waitvm<0>(); }
        __builtin_amdgcn_s_barrier();
        __builtin_amdgcn_sched_barrier(0);
        phase(bi, 1);
        __builtin_amdgcn_s_barrier();   // WAR guard before next-iter stage issue
    }

    if (MODE == 0) {
#pragma unroll
        for (int j = 0; j < NJ; j++) {
            const int col = n0 + wn * (NJ * 16) + j * 16 + lr;
            const float bj = b0[col];
#pragma unroll
            for (int i = 0; i < NI; i++) {
                const int row = m0 + wm * (NI * 16) + i * 16 + lq * 4;
#pragma unroll
                for (int r = 0; r < 4; r++)
                    Yf[(size_t)(row + r) * N + col] = acc[i][j][r] + bj;
            }
        }
    } else if (n0 < 2560) {
        // Q or K with fused RoPE
        bf16* outp; const float* bias; int ldc, c0;
        if (n0 < 2048) { outp = Yq; bias = b0; ldc = 2048; c0 = n0; }
        else           { outp = Yk; bias = b1; ldc = 512;  c0 = n0 - 2048; }
#pragma unroll
        for (int j = 0; j < NJ; j++) {
            const int col = c0 + wn * (NJ * 16) + j * 16 + lr;
            const float bj = bias[col];
            const int d2 = (col & 127) >> 1;
            const bool odd = col & 1;
            const float freq = __expf(-0.14384103622589045f * (float)d2); // ln(1e4)*2/128
#pragma unroll
            for (int i = 0; i < NI; i++) {
                const int row = m0 + wm * (NI * 16) + i * 16 + lq * 4;
#pragma unroll
                for (int r = 0; r < 4; r++) {
                    const float v = acc[i][j][r] + bj;
                    const float p = __shfl_xor(v, 1, 64);
                    const float ang = (float)((row + r) & (SS - 1)) * freq;
                    float sn, cs;
                    __sincosf(ang, &sn, &cs);
                    const float o = odd ? (p * sn + v * cs) : (v * cs - p * sn);
                    outp[(size_t)(row + r) * ldc + col] = toB(o);
                }
            }
        }
    } else {
        // V: store transposed [b][hkv][d][s]; 4 acc rows = 4 consecutive s.
        const int c0 = n0 - 2560;
#pragma unroll
        for (int j = 0; j < NJ; j++) {
            const int col = c0 + wn * (NJ * 16) + j * 16 + lr;   // 0..511
            const float bj = b2[col];
            const int hkv = col >> 7, d = col & 127;
#pragma unroll
            for (int i = 0; i < NI; i++) {
                const int row = m0 + wm * (NI * 16) + i * 16 + lq * 4;
                const int bb = row >> 11, sr = row & (SS - 1);
                union { bf16 b[4]; uint2 u; } o4;
#pragma unroll
                for (int r = 0; r < 4; r++) o4.b[r] = toB(acc[i][j][r] + bj);
                *(uint2*)(Yv + (((size_t)bb * NKV + hkv) * HD + d) * SS + sr) = o4.u;
            }
        }
    }
}

// ---------------------------------------------------------------------------
// MFMA flash attention, windowed causal, GQA (unchanged).
// ---------------------------------------------------------------------------
__global__ __launch_bounds__(256) void attn_mfma(const bf16* __restrict__ Q,
                                                 const bf16* __restrict__ K,
                                                 const bf16* __restrict__ VT,
                                                 bf16* __restrict__ Oout) {
    __shared__ bf16 Ks[64 * 128];      // [key][d], slot-swizzled
    __shared__ bf16 Vs[128 * 64];      // [d][key] (V^T), slot-swizzled
    __shared__ bf16 Ps[4 * 16 * 72];   // per-wave P tile, pad 72

    const int t = threadIdx.x;
    const int lane = t & 63;
    const int w = t >> 6;
    const int q0 = blockIdx.x * 64;
    const int h = blockIdx.y;
    const int b = blockIdx.z;
    const int hkv = h >> 2;
    const int lr = lane & 15;
    const int lq = lane >> 4;
    const float scale = 0.08838834764831845f;  // 1/sqrt(128)

    short8 aq[4];
    {
        const int q = q0 + w * 16 + lr;
        const bf16* qp = Q + (((size_t)b * SS + q) * NQ + h) * HD + lq * 8;
#pragma unroll
        for (int ks = 0; ks < 4; ks++) aq[ks] = *(const short8*)(qp + ks * 32);
    }

    const int krow = w * 16 + (lane >> 4);
    const int vrow = w * 32 + (lane >> 3);
    const bf16* Kbase = K + ((size_t)b * SS * NKV + hkv) * HD;
    const bf16* Vbase = VT + (((size_t)b * NKV + hkv) * HD) * SS;

    f32x4 Oa[8];
#pragma unroll
    for (int nb = 0; nb < 8; nb++) Oa[nb] = (f32x4)0.f;
    float mprev[4] = {-3.0e38f, -3.0e38f, -3.0e38f, -3.0e38f};
    float lsum[4] = {0.f, 0.f, 0.f, 0.f};

    bf16* Pw = Ps + w * 16 * 72;
    const int jstart = (q0 >= WINDOW) ? (q0 - WINDOW) : 0;

    for (int c0 = jstart; c0 <= q0; c0 += 64) {
        __syncthreads();
#pragma unroll
        for (int s = 0; s < 4; s++) {
            const int r_ = krow + s * 4;
            const int g_ = (lane & 15) ^ (r_ & 7);
            gld_lds16(Kbase + (size_t)(c0 + r_) * (NKV * HD) + g_ * 8,
                      Ks + (w * 16 + s * 4) * 128);
        }
#pragma unroll
        for (int s = 0; s < 4; s++) {
            const int d_ = vrow + s * 8;
            const int g_ = (lane & 7) ^ (d_ & 7);
            gld_lds16(Vbase + (size_t)d_ * SS + c0 + g_ * 8,
                      Vs + (w * 32 + s * 8) * 64);
        }
        __syncthreads();

        f32x4 sa[4];
#pragma unroll
        for (int nb = 0; nb < 4; nb++) sa[nb] = (f32x4)0.f;
#pragma unroll
        for (int ks = 0; ks < 4; ks++) {
#pragma unroll
            for (int nb = 0; nb < 4; nb++) {
                const int slot = (ks * 4 + lq) ^ (lr & 7);
                short8 bk = *(const short8*)(Ks + (nb * 16 + lr) * 128 + slot * 8);
                sa[nb] = __builtin_amdgcn_mfma_f32_16x16x32_bf16(aq[ks], bk, sa[nb], 0, 0, 0);
            }
        }

        const int rowb = q0 + w * 16 + lq * 4;
        const bool noMask = (c0 + 63 <= q0 + w * 16) &&
                            (q0 + w * 16 + 15 - c0 <= WINDOW);
        float pr[4][4], alpha[4];
#pragma unroll
        for (int r = 0; r < 4; r++) {
            const int row = rowb + r;
            float sv[4];
            float mx = -3.0e38f;
            if (noMask) {
#pragma unroll
                for (int nb = 0; nb < 4; nb++) {
                    const float s = sa[nb][r] * scale;
                    sv[nb] = s;
                    mx = fmaxf(mx, s);
                }
            } else {
#pragma unroll
                for (int nb = 0; nb < 4; nb++) {
                    const int col = c0 + nb * 16 + lr;
                    const bool valid = (col <= row) && (row - col <= WINDOW);
                    const float s = valid ? sa[nb][r] * scale : -3.0e38f;
                    sv[nb] = s;
                    mx = fmaxf(mx, s);
                }
            }
#pragma unroll
            for (int off = 1; off < 16; off <<= 1) mx = fmaxf(mx, __shfl_xor(mx, off, 64));
            const float mn = fmaxf(fmaxf(mprev[r], mx), -1.0e30f);
            alpha[r] = __expf(mprev[r] - mn);
            mprev[r] = mn;
            float rs = 0.f;
#pragma unroll
            for (int nb = 0; nb < 4; nb++) {
                const float p = __expf(sv[nb] - mn);
                pr[r][nb] = p;
                rs += p;
            }
#pragma unroll
            for (int off = 1; off < 16; off <<= 1) rs += __shfl_xor(rs, off, 64);
            lsum[r] = lsum[r] * alpha[r] + rs;
        }

#pragma unroll
        for (int r = 0; r < 4; r++)
#pragma unroll
            for (int nb = 0; nb < 4; nb++)
                Pw[(lq * 4 + r) * 72 + nb * 16 + lr] = toB(pr[r][nb]);

#pragma unroll
        for (int nb = 0; nb < 8; nb++)
#pragma unroll
            for (int r = 0; r < 4; r++) Oa[nb][r] *= alpha[r];
#pragma unroll
        for (int ks = 0; ks < 2; ks++) {
            short8 pa = *(const short8*)(Pw + lr * 72 + ks * 32 + lq * 8);
#pragma unroll
            for (int nb = 0; nb < 8; nb++) {
                const int slot = (ks * 4 + lq) ^ (lr & 7);
                short8 bv = *(const short8*)(Vs + (nb * 16 + lr) * 64 + slot * 8);
                Oa[nb] = __builtin_amdgcn_mfma_f32_16x16x32_bf16(pa, bv, Oa[nb], 0, 0, 0);
            }
        }
    }

    float linv[4];
#pragma unroll
    for (int r = 0; r < 4; r++) linv[r] = 1.f / lsum[r];
    const int rowb = q0 + w * 16 + lq * 4;
#pragma unroll
    for (int nb = 0; nb < 8; nb++)
#pragma unroll
        for (int r = 0; r < 4; r++)
            Oout[(((size_t)b * SS + rowb + r) * NQ + h) * HD + nb * 16 + lr] =
                toB(Oa[nb][r] * linv[r]);
}

// ---------------------------------------------------------------------------
extern "C" void kernel_launch(void* const* d_in, const int* in_sizes, int n_in,
                              void* d_out, int out_size, void* d_ws, size_t ws_size,
                              hipStream_t stream) {
    const float* x  = (const float*)d_in[0];
    const float* Wq = (const float*)d_in[1];
    const float* bq = (const float*)d_in[2];
    const float* Wk = (const float*)d_in[3];
    const float* bk = (const float*)d_in[4];
    const float* Wv = (const float*)d_in[5];
    const float* bv = (const float*)d_in[6];
    const float* Wo = (const float*)d_in[7];
    const float* bo = (const float*)d_in[8];
    float* out = (float*)d_out;

    const int M   = BB * SS;       // 4096
    const int DQ  = NQ * HD;       // 2048
    const int DKV = NKV * HD;      // 512
    const int NPK = DQ + 2 * DKV;  // 3072

    bf16* xb     = (bf16*)d_ws;                       // 4096*2048
    bf16* WqkvT  = xb + (size_t)M * EE;               // 3072*2048
    bf16* WoT    = WqkvT + (size_t)NPK * EE;          // 2048*2048
    bf16* Qb     = WoT + (size_t)EE * DQ;             // 4096*2048 (attn out in-place)
    bf16* Kb     = Qb + (size_t)M * DQ;               // 4096*512
    bf16* Vb     = Kb + (size_t)M * DKV;              // 4096*512  (V^T layout)

    convert_bf16<<<(M * EE / 4 + 255) / 256, 256, 0, stream>>>(x, xb, M * EE);
    convert_transpose_qkv<<<dim3(NPK / 32, EE / 32), 256, 0, stream>>>(Wq, Wk, Wv, WqkvT);
    convert_transpose<<<dim3(DQ / 32, DQ / 32), 256, 0, stream>>>(Wo, WoT, DQ, EE);

    // fused QKV projection + bias + RoPE; 256x256 tile, 192 blocks
    mfma_gemm_v3<1, 256, 256, 2><<<dim3(NPK / 256, M / 256), 512, 0, stream>>>(
        xb, WqkvT, bq, bk, bv, nullptr, Qb, Kb, Vb, M, NPK, EE);

    attn_mfma<<<dim3(SS / 64, NQ, BB), 256, 0, stream>>>(Qb, Kb, Vb, Qb);

    // out projection; 256x128 tile -> 16x16 = 256 blocks (full CU fill)
    mfma_gemm_v3<0, 256, 128, 4><<<dim3(EE / 128, M / 256), 512, 0, stream>>>(
        Qb, WoT, bo, nullptr, nullptr, out, nullptr, nullptr, nullptr, M, EE, DQ);
}